// Round 3
// baseline (9826.105 us; speedup 1.0000x reference)
//
#include <hip/hip_runtime.h>
#include <hip/hip_bf16.h>

typedef __hip_bfloat16 bf16;
typedef unsigned short u16;
using frag  = __attribute__((ext_vector_type(8))) short;   // 8 bf16
using f32x4 = __attribute__((ext_vector_type(4))) float;   // 4 fp32 acc

static constexpr int T_  = 128;
static constexpr int B_  = 512;
static constexpr int H_  = 512;
static constexpr int K_  = 512;
static constexpr int G4_ = 2048;
static constexpr int NWG = 256;
static constexpr int WPAD = 1032;                     // bf16 per LDS row: 1024 + 8 pad
static constexpr size_t SMEM_BYTES = 64 * WPAD * 2;   // 132096 B

// ---------------- setup kernels ----------------

__global__ void k_f32_to_bf16_v4(const float4* __restrict__ src,
                                 ushort4* __restrict__ dst, int n4) {
  int i = blockIdx.x * blockDim.x + threadIdx.x;
  int stride = gridDim.x * blockDim.x;
  for (; i < n4; i += stride) {
    float4 v = src[i];
    ushort4 o;
    bf16 t0 = __float2bfloat16(v.x); o.x = *reinterpret_cast<u16*>(&t0);
    bf16 t1 = __float2bfloat16(v.y); o.y = *reinterpret_cast<u16*>(&t1);
    bf16 t2 = __float2bfloat16(v.z); o.z = *reinterpret_cast<u16*>(&t2);
    bf16 t3 = __float2bfloat16(v.w); o.w = *reinterpret_cast<u16*>(&t3);
    dst[i] = o;
  }
}

__global__ void k_bias(const float* __restrict__ bih0, const float* __restrict__ bhh0,
                       const float* __restrict__ bih1, const float* __restrict__ bhh1,
                       float* __restrict__ bsum0, float* __restrict__ bsum1) {
  int i = blockIdx.x * blockDim.x + threadIdx.x;
  if (i < G4_) {
    bsum0[i] = bih0[i] + bhh0[i];
    bsum1[i] = bih1[i] + bhh1[i];
  }
}

// initial h: layer0 -> h0buf parity 0, layer1 -> h1buf parity 1
__global__ void k_init2(const float* __restrict__ h0,
                        u16* __restrict__ h0buf, u16* __restrict__ h1buf) {
  int i = blockIdx.x * blockDim.x + threadIdx.x;
  int n = B_ * H_;
  if (i < n) {
    bf16 a = __float2bfloat16(h0[i]);
    bf16 b = __float2bfloat16(h0[n + i]);
    h0buf[i] = *reinterpret_cast<u16*>(&a);          // parity 0
    h1buf[n + i] = *reinterpret_cast<u16*>(&b);      // parity 1
  }
}

__global__ void k_zero(int* p) {
  if (threadIdx.x == 0 && blockIdx.x == 0) *p = 0;
}

// ---------------- persistent LSTM kernel ----------------
// 256 WGs x 256 thr. WG -> (layer = wg>>7, bg = (wg&127)>>5, cg = wg&31).
// WG owns batch rows [bg*128, +128) x h-cols [cg*16, +16) for its layer.
// Weights for its 64 gate-rows (4 gates x 16 h-cols), W_ih || W_hh, in LDS.
// LDS row r (= gate (r>>4), h-col hbase+(r&15)):
//   u16 [0,512)    = W_ih K-elements 0..511
//   u16 [512,1024) = W_hh K-elements 0..511
//   u16 [1024,1032) = pad (never read)
// Phase p: layer0 computes t=p, layer1 computes t=p-1. 128 grid barriers.
// c-state in registers for the whole sequence. h-state: global bf16, parity dbuf.
__global__ __launch_bounds__(256, 1)
void k_main(const u16* __restrict__ latb,
            const u16* __restrict__ W0i, const u16* __restrict__ W0h,
            const u16* __restrict__ W1i, const u16* __restrict__ W1h,
            const float* __restrict__ bs0, const float* __restrict__ bs1,
            const int* __restrict__ reset,   // (T,B)
            const float* __restrict__ c0,    // (2,B,H)
            u16* __restrict__ h0buf,         // [2][B][H]
            u16* __restrict__ h1buf,         // [2][B][H]
            float* __restrict__ hidden,      // (T,B,H)
            float* __restrict__ hn,          // (2,B,H)
            float* __restrict__ cn,          // (2,B,H)
            int* __restrict__ ctr) {
  extern __shared__ char smem_raw[];
  u16* wlds = (u16*)smem_raw;                // [64][WPAD]
  __shared__ int rstlds[128];

  const int tid   = threadIdx.x;
  const int wg    = blockIdx.x;
  const int layer = wg >> 7;
  const int idx   = wg & 127;
  const int bg    = idx >> 5;
  const int cg    = idx & 31;
  const int hbase = cg * 16;
  const int rowbase = bg * 128;
  const int wave  = tid >> 6;
  const int lane  = tid & 63;
  const int r16   = lane & 15;
  const int kq    = lane >> 4;
  const int wrow_local = wave * 32;            // wave's batch offset within WG
  const int wrow0 = rowbase + wrow_local;

  const u16* Wih = layer ? W1i : W0i;
  const u16* Whh = layer ? W1h : W0h;
  const float* bs = layer ? bs1 : bs0;
  u16* hself = layer ? h1buf : h0buf;

  // ---- stage weights into LDS (once): row r -> gate r>>4, h-col hbase + (r&15)
  for (int c = 0; c < 32; ++c) {
    int chunk = c * 256 + tid;                 // 8192 chunks of 16B
    int row = chunk >> 7;                      // 128 chunks per row
    int inb = (chunk & 127) * 16;              // byte offset in row (0..2047)
    int grow = (row >> 4) * H_ + hbase + (row & 15);
    const char* src = (inb < 1024)
        ? (const char*)(Wih + (size_t)grow * K_) + inb
        : (const char*)(Whh + (size_t)grow * K_) + (inb - 1024);
    char* dst = (char*)(wlds + (size_t)row * WPAD) + inb;
    *(float4*)dst = *(const float4*)src;
  }

  // per-lane gate biases (col = hbase + r16)
  float bias[4];
  #pragma unroll
  for (int g = 0; g < 4; ++g) bias[g] = bs[g * H_ + hbase + r16];

  // c-state registers: (mi, j) -> row = wrow0 + mi*16 + kq*4 + j, col = hbase + r16
  float creg[2][4];
  #pragma unroll
  for (int mi = 0; mi < 2; ++mi)
    #pragma unroll
    for (int j = 0; j < 4; ++j)
      creg[mi][j] = c0[((size_t)layer * B_ + (wrow0 + mi * 16 + kq * 4 + j)) * H_
                       + hbase + r16];

  __syncthreads();

  const u16* wb = wlds + (size_t)r16 * WPAD + kq * 8;

  for (int p = 0; p <= T_; ++p) {
    const int t = layer ? (p - 1) : p;
    if (t >= 0 && t < T_) {
      if (tid < 128) rstlds[tid] = reset[(size_t)t * B_ + rowbase + tid];
      __syncthreads();

      const u16* X  = layer ? (h0buf + (size_t)(p & 1) * B_ * H_)
                            : (latb + (size_t)t * B_ * K_);
      const u16* Hp = hself + (size_t)(p & 1) * B_ * H_;
      u16* Hn       = hself + (size_t)((p + 1) & 1) * B_ * H_;

      const int ra0 = rstlds[wrow_local + r16];
      const int ra1 = rstlds[wrow_local + 16 + r16];

      const u16* x0  = X  + (size_t)(wrow0 + r16) * K_ + kq * 8;
      const u16* x1  = X  + (size_t)(wrow0 + 16 + r16) * K_ + kq * 8;
      const u16* hp0 = Hp + (size_t)(wrow0 + r16) * H_ + kq * 8;
      const u16* hp1 = Hp + (size_t)(wrow0 + 16 + r16) * H_ + kq * 8;

      f32x4 acc[2][4] = {};
      const frag zf = {};

      // x part: K = 512  (W_ih at LDS row u16-offset [0,512))
      #pragma unroll 4
      for (int kb = 0; kb < K_; kb += 32) {
        frag a0 = *reinterpret_cast<const frag*>(x0 + kb);
        frag a1 = *reinterpret_cast<const frag*>(x1 + kb);
        #pragma unroll
        for (int ni = 0; ni < 4; ++ni) {
          frag b = *reinterpret_cast<const frag*>(wb + (size_t)ni * 16 * WPAD + kb);
          acc[0][ni] = __builtin_amdgcn_mfma_f32_16x16x32_bf16(a0, b, acc[0][ni], 0, 0, 0);
          acc[1][ni] = __builtin_amdgcn_mfma_f32_16x16x32_bf16(a1, b, acc[1][ni], 0, 0, 0);
        }
      }
      // h part: K = 512, reset-masked rows (W_hh at LDS row u16-offset [512,1024))
      #pragma unroll 4
      for (int kb = 0; kb < K_; kb += 32) {
        frag a0 = ra0 ? zf : *reinterpret_cast<const frag*>(hp0 + kb);
        frag a1 = ra1 ? zf : *reinterpret_cast<const frag*>(hp1 + kb);
        #pragma unroll
        for (int ni = 0; ni < 4; ++ni) {
          frag b = *reinterpret_cast<const frag*>(wb + (size_t)ni * 16 * WPAD + 512 + kb);
          acc[0][ni] = __builtin_amdgcn_mfma_f32_16x16x32_bf16(a0, b, acc[0][ni], 0, 0, 0);
          acc[1][ni] = __builtin_amdgcn_mfma_f32_16x16x32_bf16(a1, b, acc[1][ni], 0, 0, 0);
        }
      }

      // cell elementwise: fully lane-local (ni = gate, same col r16)
      float* hidden_t = hidden + (size_t)t * B_ * H_;
      #pragma unroll
      for (int mi = 0; mi < 2; ++mi) {
        #pragma unroll
        for (int j = 0; j < 4; ++j) {
          const int lrow = wrow_local + mi * 16 + kq * 4 + j;
          const int row  = rowbase + lrow;
          const int col  = hbase + r16;
          float gi = acc[mi][0][j] + bias[0];
          float gf = acc[mi][1][j] + bias[1];
          float gg = acc[mi][2][j] + bias[2];
          float go = acc[mi][3][j] + bias[3];
          float iv = 1.f / (1.f + __expf(-gi));
          float fv = 1.f / (1.f + __expf(-gf));
          float gv = 1.f - 2.f / (__expf(2.f * gg) + 1.f);   // tanh
          float ov = 1.f / (1.f + __expf(-go));
          float ce = rstlds[lrow] ? 0.f : creg[mi][j];
          float cnew = fv * ce + iv * gv;
          float hnew = ov * (1.f - 2.f / (__expf(2.f * cnew) + 1.f));
          creg[mi][j] = cnew;
          const size_t off = (size_t)row * H_ + col;
          bf16 hb = __float2bfloat16(hnew);
          Hn[off] = *reinterpret_cast<u16*>(&hb);
          if (layer) hidden_t[off] = hnew;
          if (t == T_ - 1) {
            hn[(size_t)layer * B_ * H_ + off] = hnew;
            cn[(size_t)layer * B_ * H_ + off] = cnew;
          }
        }
      }
    }

    // grid barrier between phases (monotonic counter, agent scope)
    if (p < T_) {
      __threadfence();          // release: drain stores, write-back L2
      __syncthreads();
      if (tid == 0) {
        __hip_atomic_fetch_add(ctr, 1, __ATOMIC_ACQ_REL, __HIP_MEMORY_SCOPE_AGENT);
        const int target = NWG * (p + 1);
        while (__hip_atomic_load(ctr, __ATOMIC_ACQUIRE, __HIP_MEMORY_SCOPE_AGENT) < target)
          __builtin_amdgcn_s_sleep(1);
      }
      __syncthreads();
      __threadfence();          // acquire: invalidate stale L1/L2 lines
    }
  }
}

// ---------------- host ----------------

extern "C" void kernel_launch(void* const* d_in, const int* in_sizes, int n_in,
                              void* d_out, int out_size, void* d_ws, size_t ws_size,
                              hipStream_t stream) {
  (void)in_sizes; (void)n_in; (void)out_size; (void)ws_size;

  const float* latent = (const float*)d_in[0];
  const float* h0in   = (const float*)d_in[1];
  const float* c0in   = (const float*)d_in[2];
  const int*   reset  = (const int*)d_in[3];
  const float* W_ih0  = (const float*)d_in[4];
  const float* W_hh0  = (const float*)d_in[5];
  const float* b_ih0  = (const float*)d_in[6];
  const float* b_hh0  = (const float*)d_in[7];
  const float* W_ih1  = (const float*)d_in[8];
  const float* W_hh1  = (const float*)d_in[9];
  const float* b_ih1  = (const float*)d_in[10];
  const float* b_hh1  = (const float*)d_in[11];

  float* out    = (float*)d_out;
  float* hidden = out;                               // (T,B,H)
  float* hn     = out + (size_t)T_ * B_ * H_;        // (2,B,H)
  float* cn     = hn + (size_t)2 * B_ * H_;          // (2,B,H)

  // workspace layout
  char* ws = (char*)d_ws;
  u16* latb  = (u16*)ws;                             // T*B*K bf16 (64 MiB)
  u16* wih0b = latb + (size_t)T_ * B_ * K_;
  u16* whh0b = wih0b + (size_t)G4_ * K_;
  u16* wih1b = whh0b + (size_t)G4_ * K_;
  u16* whh1b = wih1b + (size_t)G4_ * K_;
  float* bsum0 = (float*)(whh1b + (size_t)G4_ * K_);
  float* bsum1 = bsum0 + G4_;
  u16* h0buf = (u16*)(bsum1 + G4_);                  // [2][B][H]
  u16* h1buf = h0buf + (size_t)2 * B_ * H_;
  int* ctr   = (int*)(h1buf + (size_t)2 * B_ * H_);

  // conversions / init (stream-ordered)
  int n_lat4 = T_ * B_ * K_ / 4;
  k_f32_to_bf16_v4<<<2048, 256, 0, stream>>>((const float4*)latent, (ushort4*)latb, n_lat4);
  int n_w4 = G4_ * K_ / 4;
  k_f32_to_bf16_v4<<<256, 256, 0, stream>>>((const float4*)W_ih0, (ushort4*)wih0b, n_w4);
  k_f32_to_bf16_v4<<<256, 256, 0, stream>>>((const float4*)W_hh0, (ushort4*)whh0b, n_w4);
  k_f32_to_bf16_v4<<<256, 256, 0, stream>>>((const float4*)W_ih1, (ushort4*)wih1b, n_w4);
  k_f32_to_bf16_v4<<<256, 256, 0, stream>>>((const float4*)W_hh1, (ushort4*)whh1b, n_w4);
  k_bias<<<(G4_ + 255) / 256, 256, 0, stream>>>(b_ih0, b_hh0, b_ih1, b_hh1, bsum0, bsum1);
  k_init2<<<(B_ * H_ + 255) / 256, 256, 0, stream>>>(h0in, h0buf, h1buf);
  k_zero<<<1, 1, 0, stream>>>(ctr);

  // persistent cooperative kernel
  hipFuncSetAttribute((const void*)k_main, hipFuncAttributeMaxDynamicSharedMemorySize,
                      (int)SMEM_BYTES);
  void* args[] = { (void*)&latb, (void*)&wih0b, (void*)&whh0b, (void*)&wih1b, (void*)&whh1b,
                   (void*)&bsum0, (void*)&bsum1, (void*)&reset, (void*)&c0in,
                   (void*)&h0buf, (void*)&h1buf, (void*)&hidden, (void*)&hn, (void*)&cn,
                   (void*)&ctr };
  hipLaunchCooperativeKernel((void*)k_main, dim3(NWG), dim3(256), args,
                             (unsigned int)SMEM_BYTES, stream);
}

// Round 4
// 5117.926 us; speedup vs baseline: 1.9199x; 1.9199x over previous
//
#include <hip/hip_runtime.h>
#include <hip/hip_bf16.h>

typedef __hip_bfloat16 bf16;
typedef unsigned short u16;
using frag  = __attribute__((ext_vector_type(8))) short;   // 8 bf16
using f32x4 = __attribute__((ext_vector_type(4))) float;   // 4 fp32 acc

static constexpr int T_  = 128;
static constexpr int B_  = 512;
static constexpr int H_  = 512;
static constexpr int K_  = 512;
static constexpr int G4_ = 2048;
static constexpr int NWG = 256;
static constexpr int WPAD = 1032;                     // bf16 per LDS row: 1024 + 8 pad
static constexpr size_t SMEM_BYTES = 64 * WPAD * 2;   // 132096 B

// ---------------- setup kernels ----------------

__global__ void k_f32_to_bf16_v4(const float4* __restrict__ src,
                                 ushort4* __restrict__ dst, int n4) {
  int i = blockIdx.x * blockDim.x + threadIdx.x;
  int stride = gridDim.x * blockDim.x;
  for (; i < n4; i += stride) {
    float4 v = src[i];
    ushort4 o;
    bf16 t0 = __float2bfloat16(v.x); o.x = *reinterpret_cast<u16*>(&t0);
    bf16 t1 = __float2bfloat16(v.y); o.y = *reinterpret_cast<u16*>(&t1);
    bf16 t2 = __float2bfloat16(v.z); o.z = *reinterpret_cast<u16*>(&t2);
    bf16 t3 = __float2bfloat16(v.w); o.w = *reinterpret_cast<u16*>(&t3);
    dst[i] = o;
  }
}

__global__ void k_bias(const float* __restrict__ bih0, const float* __restrict__ bhh0,
                       const float* __restrict__ bih1, const float* __restrict__ bhh1,
                       float* __restrict__ bsum0, float* __restrict__ bsum1) {
  int i = blockIdx.x * blockDim.x + threadIdx.x;
  if (i < G4_) {
    bsum0[i] = bih0[i] + bhh0[i];
    bsum1[i] = bih1[i] + bhh1[i];
  }
}

// initial h: layer0 -> h0buf parity 0, layer1 -> h1buf parity 1
__global__ void k_init2(const float* __restrict__ h0,
                        u16* __restrict__ h0buf, u16* __restrict__ h1buf) {
  int i = blockIdx.x * blockDim.x + threadIdx.x;
  int n = B_ * H_;
  if (i < n) {
    bf16 a = __float2bfloat16(h0[i]);
    bf16 b = __float2bfloat16(h0[n + i]);
    h0buf[i] = *reinterpret_cast<u16*>(&a);          // parity 0
    h1buf[n + i] = *reinterpret_cast<u16*>(&b);      // parity 1
  }
}

__global__ void k_zero(int* p) {
  if (threadIdx.x == 0 && blockIdx.x == 0) *p = 0;
}

// ---------------- persistent LSTM kernel ----------------
// 256 WGs x 256 thr. XCD-locality mapping (wg%8 ~ XCD round-robin):
//   lb = wg & 7 : layer = lb>>2, bg = lb&3  -> one (layer,bg) per XCD
//   cg = wg >> 3 (0..31)                    -> 32 column-WGs co-located on XCD
// WG owns batch rows [bg*128,+128) x h-cols [cg*16,+16) for its layer.
// Weights for its 64 gate-rows (4 gates x 16 h-cols), W_ih || W_hh, in LDS:
//   LDS row r: u16 [0,512) = W_ih k=0..511 ; [512,1024) = W_hh ; [1024,1032) pad
// Phase p: layer0 computes t=p, layer1 computes t=p-1. 128 grid barriers.
// Barrier: RELAXED add + RELAXED poll; ONE agent release fence before arrival,
// ONE agent acquire fence after departure (avoids per-poll L2 invalidate).
// c-state in registers for the whole sequence. h-state: global bf16, parity dbuf.
__global__ __launch_bounds__(256, 1)
void k_main(const u16* __restrict__ latb,
            const u16* __restrict__ W0i, const u16* __restrict__ W0h,
            const u16* __restrict__ W1i, const u16* __restrict__ W1h,
            const float* __restrict__ bs0, const float* __restrict__ bs1,
            const int* __restrict__ reset,   // (T,B)
            const float* __restrict__ c0,    // (2,B,H)
            u16* __restrict__ h0buf,         // [2][B][H]
            u16* __restrict__ h1buf,         // [2][B][H]
            float* __restrict__ hidden,      // (T,B,H)
            float* __restrict__ hn,          // (2,B,H)
            float* __restrict__ cn,          // (2,B,H)
            int* __restrict__ ctr) {
  extern __shared__ char smem_raw[];
  u16* wlds = (u16*)smem_raw;                // [64][WPAD]
  __shared__ int rstlds[128];

  const int tid   = threadIdx.x;
  const int wg    = blockIdx.x;
  const int lb    = wg & 7;
  const int layer = lb >> 2;
  const int bg    = lb & 3;
  const int cg    = wg >> 3;
  const int hbase = cg * 16;
  const int rowbase = bg * 128;
  const int wave  = tid >> 6;
  const int lane  = tid & 63;
  const int r16   = lane & 15;
  const int kq    = lane >> 4;
  const int wrow_local = wave * 32;            // wave's batch offset within WG
  const int wrow0 = rowbase + wrow_local;

  const u16* Wih = layer ? W1i : W0i;
  const u16* Whh = layer ? W1h : W0h;
  const float* bs = layer ? bs1 : bs0;
  u16* hself = layer ? h1buf : h0buf;

  // ---- stage weights into LDS (once): row r -> gate r>>4, h-col hbase + (r&15)
  for (int c = 0; c < 32; ++c) {
    int chunk = c * 256 + tid;                 // 8192 chunks of 16B
    int row = chunk >> 7;                      // 128 chunks per row
    int inb = (chunk & 127) * 16;              // byte offset in row (0..2047)
    int grow = (row >> 4) * H_ + hbase + (row & 15);
    const char* src = (inb < 1024)
        ? (const char*)(Wih + (size_t)grow * K_) + inb
        : (const char*)(Whh + (size_t)grow * K_) + (inb - 1024);
    char* dst = (char*)(wlds + (size_t)row * WPAD) + inb;
    *(float4*)dst = *(const float4*)src;
  }

  // per-lane gate biases (col = hbase + r16)
  float bias[4];
  #pragma unroll
  for (int g = 0; g < 4; ++g) bias[g] = bs[g * H_ + hbase + r16];

  // c-state registers: (mi, j) -> row = wrow0 + mi*16 + kq*4 + j, col = hbase + r16
  float creg[2][4];
  #pragma unroll
  for (int mi = 0; mi < 2; ++mi)
    #pragma unroll
    for (int j = 0; j < 4; ++j)
      creg[mi][j] = c0[((size_t)layer * B_ + (wrow0 + mi * 16 + kq * 4 + j)) * H_
                       + hbase + r16];

  __syncthreads();

  const u16* wb = wlds + (size_t)r16 * WPAD + kq * 8;

  for (int p = 0; p <= T_; ++p) {
    const int t = layer ? (p - 1) : p;
    if (t >= 0 && t < T_) {
      if (tid < 128) rstlds[tid] = reset[(size_t)t * B_ + rowbase + tid];
      __syncthreads();

      const u16* X  = layer ? (h0buf + (size_t)(p & 1) * B_ * H_)
                            : (latb + (size_t)t * B_ * K_);
      const u16* Hp = hself + (size_t)(p & 1) * B_ * H_;
      u16* Hn       = hself + (size_t)((p + 1) & 1) * B_ * H_;

      const int ra0 = rstlds[wrow_local + r16];
      const int ra1 = rstlds[wrow_local + 16 + r16];

      const u16* x0  = X  + (size_t)(wrow0 + r16) * K_ + kq * 8;
      const u16* x1  = X  + (size_t)(wrow0 + 16 + r16) * K_ + kq * 8;
      const u16* hp0 = Hp + (size_t)(wrow0 + r16) * H_ + kq * 8;
      const u16* hp1 = Hp + (size_t)(wrow0 + 16 + r16) * H_ + kq * 8;

      f32x4 acc[2][4] = {};
      const frag zf = {};

      // merged x+h K-loop: 4 independent global loads per iter in flight
      #pragma unroll 4
      for (int kb = 0; kb < K_; kb += 32) {
        frag a0  = *reinterpret_cast<const frag*>(x0 + kb);
        frag a1  = *reinterpret_cast<const frag*>(x1 + kb);
        frag ah0 = ra0 ? zf : *reinterpret_cast<const frag*>(hp0 + kb);
        frag ah1 = ra1 ? zf : *reinterpret_cast<const frag*>(hp1 + kb);
        #pragma unroll
        for (int ni = 0; ni < 4; ++ni) {
          frag bx = *reinterpret_cast<const frag*>(wb + (size_t)ni * 16 * WPAD + kb);
          frag bh = *reinterpret_cast<const frag*>(wb + (size_t)ni * 16 * WPAD + 512 + kb);
          acc[0][ni] = __builtin_amdgcn_mfma_f32_16x16x32_bf16(a0,  bx, acc[0][ni], 0, 0, 0);
          acc[1][ni] = __builtin_amdgcn_mfma_f32_16x16x32_bf16(a1,  bx, acc[1][ni], 0, 0, 0);
          acc[0][ni] = __builtin_amdgcn_mfma_f32_16x16x32_bf16(ah0, bh, acc[0][ni], 0, 0, 0);
          acc[1][ni] = __builtin_amdgcn_mfma_f32_16x16x32_bf16(ah1, bh, acc[1][ni], 0, 0, 0);
        }
      }

      // cell elementwise: fully lane-local (ni = gate, same col r16)
      float* hidden_t = hidden + (size_t)t * B_ * H_;
      #pragma unroll
      for (int mi = 0; mi < 2; ++mi) {
        #pragma unroll
        for (int j = 0; j < 4; ++j) {
          const int lrow = wrow_local + mi * 16 + kq * 4 + j;
          const int row  = rowbase + lrow;
          const int col  = hbase + r16;
          float gi = acc[mi][0][j] + bias[0];
          float gf = acc[mi][1][j] + bias[1];
          float gg = acc[mi][2][j] + bias[2];
          float go = acc[mi][3][j] + bias[3];
          float iv = 1.f / (1.f + __expf(-gi));
          float fv = 1.f / (1.f + __expf(-gf));
          float gv = 1.f - 2.f / (__expf(2.f * gg) + 1.f);   // tanh
          float ov = 1.f / (1.f + __expf(-go));
          float ce = rstlds[lrow] ? 0.f : creg[mi][j];
          float cnew = fv * ce + iv * gv;
          float hnew = ov * (1.f - 2.f / (__expf(2.f * cnew) + 1.f));
          creg[mi][j] = cnew;
          const size_t off = (size_t)row * H_ + col;
          bf16 hb = __float2bfloat16(hnew);
          Hn[off] = *reinterpret_cast<u16*>(&hb);
          if (layer) hidden_t[off] = hnew;
          if (t == T_ - 1) {
            hn[(size_t)layer * B_ * H_ + off] = hnew;
            cn[(size_t)layer * B_ * H_ + off] = cnew;
          }
        }
      }
    }

    // grid barrier: relaxed add + relaxed poll, single release/acquire per phase
    if (p < T_) {
      __builtin_amdgcn_fence(__ATOMIC_RELEASE, "agent");  // one L2 writeback
      __syncthreads();
      if (tid == 0) {
        __hip_atomic_fetch_add(ctr, 1, __ATOMIC_RELAXED, __HIP_MEMORY_SCOPE_AGENT);
        const int target = NWG * (p + 1);
        while (__hip_atomic_load(ctr, __ATOMIC_RELAXED, __HIP_MEMORY_SCOPE_AGENT) < target)
          __builtin_amdgcn_s_sleep(2);
      }
      __syncthreads();
      __builtin_amdgcn_fence(__ATOMIC_ACQUIRE, "agent"); // one L2/L1 invalidate
    }
  }
}

// ---------------- host ----------------

extern "C" void kernel_launch(void* const* d_in, const int* in_sizes, int n_in,
                              void* d_out, int out_size, void* d_ws, size_t ws_size,
                              hipStream_t stream) {
  (void)in_sizes; (void)n_in; (void)out_size; (void)ws_size;

  const float* latent = (const float*)d_in[0];
  const float* h0in   = (const float*)d_in[1];
  const float* c0in   = (const float*)d_in[2];
  const int*   reset  = (const int*)d_in[3];
  const float* W_ih0  = (const float*)d_in[4];
  const float* W_hh0  = (const float*)d_in[5];
  const float* b_ih0  = (const float*)d_in[6];
  const float* b_hh0  = (const float*)d_in[7];
  const float* W_ih1  = (const float*)d_in[8];
  const float* W_hh1  = (const float*)d_in[9];
  const float* b_ih1  = (const float*)d_in[10];
  const float* b_hh1  = (const float*)d_in[11];

  float* out    = (float*)d_out;
  float* hidden = out;                               // (T,B,H)
  float* hn     = out + (size_t)T_ * B_ * H_;        // (2,B,H)
  float* cn     = hn + (size_t)2 * B_ * H_;          // (2,B,H)

  // workspace layout
  char* ws = (char*)d_ws;
  u16* latb  = (u16*)ws;                             // T*B*K bf16 (64 MiB)
  u16* wih0b = latb + (size_t)T_ * B_ * K_;
  u16* whh0b = wih0b + (size_t)G4_ * K_;
  u16* wih1b = whh0b + (size_t)G4_ * K_;
  u16* whh1b = wih1b + (size_t)G4_ * K_;
  float* bsum0 = (float*)(whh1b + (size_t)G4_ * K_);
  float* bsum1 = bsum0 + G4_;
  u16* h0buf = (u16*)(bsum1 + G4_);                  // [2][B][H]
  u16* h1buf = h0buf + (size_t)2 * B_ * H_;
  int* ctr   = (int*)(h1buf + (size_t)2 * B_ * H_);

  // conversions / init (stream-ordered)
  int n_lat4 = T_ * B_ * K_ / 4;
  k_f32_to_bf16_v4<<<2048, 256, 0, stream>>>((const float4*)latent, (ushort4*)latb, n_lat4);
  int n_w4 = G4_ * K_ / 4;
  k_f32_to_bf16_v4<<<256, 256, 0, stream>>>((const float4*)W_ih0, (ushort4*)wih0b, n_w4);
  k_f32_to_bf16_v4<<<256, 256, 0, stream>>>((const float4*)W_hh0, (ushort4*)whh0b, n_w4);
  k_f32_to_bf16_v4<<<256, 256, 0, stream>>>((const float4*)W_ih1, (ushort4*)wih1b, n_w4);
  k_f32_to_bf16_v4<<<256, 256, 0, stream>>>((const float4*)W_hh1, (ushort4*)whh1b, n_w4);
  k_bias<<<(G4_ + 255) / 256, 256, 0, stream>>>(b_ih0, b_hh0, b_ih1, b_hh1, bsum0, bsum1);
  k_init2<<<(B_ * H_ + 255) / 256, 256, 0, stream>>>(h0in, h0buf, h1buf);
  k_zero<<<1, 1, 0, stream>>>(ctr);

  // persistent cooperative kernel
  hipFuncSetAttribute((const void*)k_main, hipFuncAttributeMaxDynamicSharedMemorySize,
                      (int)SMEM_BYTES);
  void* args[] = { (void*)&latb, (void*)&wih0b, (void*)&whh0b, (void*)&wih1b, (void*)&whh1b,
                   (void*)&bsum0, (void*)&bsum1, (void*)&reset, (void*)&c0in,
                   (void*)&h0buf, (void*)&h1buf, (void*)&hidden, (void*)&hn, (void*)&cn,
                   (void*)&ctr };
  hipLaunchCooperativeKernel((void*)k_main, dim3(NWG), dim3(256), args,
                             (unsigned int)SMEM_BYTES, stream);
}

// Round 5
// 1998.819 us; speedup vs baseline: 4.9160x; 2.5605x over previous
//
#include <hip/hip_runtime.h>
#include <hip/hip_bf16.h>

typedef __hip_bfloat16 bf16;
typedef unsigned short u16;
typedef unsigned long long u64;
using frag  = __attribute__((ext_vector_type(8))) short;   // 8 bf16
using f32x4 = __attribute__((ext_vector_type(4))) float;   // 4 fp32 acc

static constexpr int T_  = 128;
static constexpr int B_  = 512;
static constexpr int H_  = 512;
static constexpr int K_  = 512;
static constexpr int G4_ = 2048;
static constexpr int NWG = 256;
static constexpr int WPAD = 1032;                     // bf16 per LDS row: 1024 + 8 pad
static constexpr size_t SMEM_BYTES = 64 * WPAD * 2;   // 132096 B

// coherent (agent-scope, L2-bypassing) 16B load as 2x b64 relaxed atomics
__device__ __forceinline__ frag ld_coh(const u16* p) {
  u64 lo = __hip_atomic_load((const u64*)p,       __ATOMIC_RELAXED, __HIP_MEMORY_SCOPE_AGENT);
  u64 hi = __hip_atomic_load((const u64*)(p + 4), __ATOMIC_RELAXED, __HIP_MEMORY_SCOPE_AGENT);
  union { u64 q[2]; frag f; } u;
  u.q[0] = lo; u.q[1] = hi;
  return u.f;
}

// ---------------- setup kernels ----------------

__global__ void k_f32_to_bf16_v4(const float4* __restrict__ src,
                                 ushort4* __restrict__ dst, int n4) {
  int i = blockIdx.x * blockDim.x + threadIdx.x;
  int stride = gridDim.x * blockDim.x;
  for (; i < n4; i += stride) {
    float4 v = src[i];
    ushort4 o;
    bf16 t0 = __float2bfloat16(v.x); o.x = *reinterpret_cast<u16*>(&t0);
    bf16 t1 = __float2bfloat16(v.y); o.y = *reinterpret_cast<u16*>(&t1);
    bf16 t2 = __float2bfloat16(v.z); o.z = *reinterpret_cast<u16*>(&t2);
    bf16 t3 = __float2bfloat16(v.w); o.w = *reinterpret_cast<u16*>(&t3);
    dst[i] = o;
  }
}

__global__ void k_bias(const float* __restrict__ bih0, const float* __restrict__ bhh0,
                       const float* __restrict__ bih1, const float* __restrict__ bhh1,
                       float* __restrict__ bsum0, float* __restrict__ bsum1) {
  int i = blockIdx.x * blockDim.x + threadIdx.x;
  if (i < G4_) {
    bsum0[i] = bih0[i] + bhh0[i];
    bsum1[i] = bih1[i] + bhh1[i];
  }
}

// initial h: layer0 -> h0buf parity 0, layer1 -> h1buf parity 1
__global__ void k_init2(const float* __restrict__ h0,
                        u16* __restrict__ h0buf, u16* __restrict__ h1buf) {
  int i = blockIdx.x * blockDim.x + threadIdx.x;
  int n = B_ * H_;
  if (i < n) {
    bf16 a = __float2bfloat16(h0[i]);
    bf16 b = __float2bfloat16(h0[n + i]);
    h0buf[i] = *reinterpret_cast<u16*>(&a);          // parity 0
    h1buf[n + i] = *reinterpret_cast<u16*>(&b);      // parity 1
  }
}

__global__ void k_zero(int* p) {
  int i = blockIdx.x * blockDim.x + threadIdx.x;
  if (i < 128) p[i] = 0;
}

// ---------------- persistent LSTM kernel ----------------
// 256 WGs x 256 thr. XCD-locality mapping (wg%8 ~ XCD round-robin):
//   lb = wg & 7 : layer = lb>>2, bg = lb&3 ; cg = wg >> 3 (0..31)
// WG owns batch rows [bg*128,+128) x h-cols [cg*16,+16) for its layer.
// Weights (64 gate-rows, W_ih||W_hh) in LDS, staged once, reused 128 steps.
// Phase p: layer0 computes t=p, layer1 computes t=p-1.
// Sync: 4 independent pair-domains (layer0-group-b <-> layer1-group-b, 64 WGs).
//   Per phase: each WG adds 1 to its pair counter (relaxed agent atomic,
//   fire-and-forget), polls until ctr >= 64*(p+1). NO cache-maintenance
//   fences: all cross-WG data (h0buf/h1buf) moves via agent-scope relaxed
//   atomics (sc0/sc1: write-through + L1/L2-bypass -> coherent at L3).
// c-state in registers for the whole sequence.
__global__ __launch_bounds__(256, 1)
void k_main(const u16* __restrict__ latb,
            const u16* __restrict__ W0i, const u16* __restrict__ W0h,
            const u16* __restrict__ W1i, const u16* __restrict__ W1h,
            const float* __restrict__ bs0, const float* __restrict__ bs1,
            const int* __restrict__ reset,   // (T,B)
            const float* __restrict__ c0,    // (2,B,H)
            u16* __restrict__ h0buf,         // [2][B][H]
            u16* __restrict__ h1buf,         // [2][B][H]
            float* __restrict__ hidden,      // (T,B,H)
            float* __restrict__ hn,          // (2,B,H)
            float* __restrict__ cn,          // (2,B,H)
            int* __restrict__ ctr) {         // 4 pair counters, stride 32 ints
  extern __shared__ char smem_raw[];
  u16* wlds = (u16*)smem_raw;                // [64][WPAD]
  __shared__ int rstlds[128];
  __shared__ u16 hstage[4][32][16];          // per-wave h packing tile

  const int tid   = threadIdx.x;
  const int wg    = blockIdx.x;
  const int lb    = wg & 7;
  const int layer = lb >> 2;
  const int bg    = lb & 3;
  const int cg    = wg >> 3;
  const int hbase = cg * 16;
  const int rowbase = bg * 128;
  const int wave  = tid >> 6;
  const int lane  = tid & 63;
  const int r16   = lane & 15;
  const int kq    = lane >> 4;
  const int wrow_local = wave * 32;            // wave's batch offset within WG
  const int wrow0 = rowbase + wrow_local;

  const u16* Wih = layer ? W1i : W0i;
  const u16* Whh = layer ? W1h : W0h;
  const float* bs = layer ? bs1 : bs0;
  u16* hself = layer ? h1buf : h0buf;
  int* pairctr = ctr + bg * 32;

  // ---- stage weights into LDS (once): row r -> gate r>>4, h-col hbase + (r&15)
  for (int c = 0; c < 32; ++c) {
    int chunk = c * 256 + tid;                 // 8192 chunks of 16B
    int row = chunk >> 7;                      // 128 chunks per row
    int inb = (chunk & 127) * 16;              // byte offset in row (0..2047)
    int grow = (row >> 4) * H_ + hbase + (row & 15);
    const char* src = (inb < 1024)
        ? (const char*)(Wih + (size_t)grow * K_) + inb
        : (const char*)(Whh + (size_t)grow * K_) + (inb - 1024);
    char* dst = (char*)(wlds + (size_t)row * WPAD) + inb;
    *(float4*)dst = *(const float4*)src;
  }

  // per-lane gate biases (col = hbase + r16)
  float bias[4];
  #pragma unroll
  for (int g = 0; g < 4; ++g) bias[g] = bs[g * H_ + hbase + r16];

  // c-state registers: (mi, j) -> row = wrow0 + mi*16 + kq*4 + j, col = hbase + r16
  float creg[2][4];
  #pragma unroll
  for (int mi = 0; mi < 2; ++mi)
    #pragma unroll
    for (int j = 0; j < 4; ++j)
      creg[mi][j] = c0[((size_t)layer * B_ + (wrow0 + mi * 16 + kq * 4 + j)) * H_
                       + hbase + r16];

  __syncthreads();

  const u16* wb = wlds + (size_t)r16 * WPAD + kq * 8;

  for (int p = 0; p <= T_; ++p) {
    const int t = layer ? (p - 1) : p;
    if (t >= 0 && t < T_) {
      if (tid < 128) rstlds[tid] = reset[(size_t)t * B_ + rowbase + tid];
      __syncthreads();

      const u16* X  = layer ? (h0buf + (size_t)(p & 1) * B_ * H_)
                            : (latb + (size_t)t * B_ * K_);
      const u16* Hp = hself + (size_t)(p & 1) * B_ * H_;
      u16* Hn       = hself + (size_t)((p + 1) & 1) * B_ * H_;

      const int ra0 = rstlds[wrow_local + r16];
      const int ra1 = rstlds[wrow_local + 16 + r16];

      const u16* x0  = X  + (size_t)(wrow0 + r16) * K_ + kq * 8;
      const u16* x1  = X  + (size_t)(wrow0 + 16 + r16) * K_ + kq * 8;
      const u16* hp0 = Hp + (size_t)(wrow0 + r16) * H_ + kq * 8;
      const u16* hp1 = Hp + (size_t)(wrow0 + 16 + r16) * H_ + kq * 8;

      f32x4 acc[2][4] = {};
      const frag zf = {};

      if (layer == 0) {
        // x = latent: plain cached frag loads; h = h0buf: coherent loads
        #pragma unroll 4
        for (int kb = 0; kb < K_; kb += 32) {
          frag a0  = *reinterpret_cast<const frag*>(x0 + kb);
          frag a1  = *reinterpret_cast<const frag*>(x1 + kb);
          frag ah0 = ra0 ? zf : ld_coh(hp0 + kb);
          frag ah1 = ra1 ? zf : ld_coh(hp1 + kb);
          #pragma unroll
          for (int ni = 0; ni < 4; ++ni) {
            frag bx = *reinterpret_cast<const frag*>(wb + (size_t)ni * 16 * WPAD + kb);
            frag bh = *reinterpret_cast<const frag*>(wb + (size_t)ni * 16 * WPAD + 512 + kb);
            acc[0][ni] = __builtin_amdgcn_mfma_f32_16x16x32_bf16(a0,  bx, acc[0][ni], 0, 0, 0);
            acc[1][ni] = __builtin_amdgcn_mfma_f32_16x16x32_bf16(a1,  bx, acc[1][ni], 0, 0, 0);
            acc[0][ni] = __builtin_amdgcn_mfma_f32_16x16x32_bf16(ah0, bh, acc[0][ni], 0, 0, 0);
            acc[1][ni] = __builtin_amdgcn_mfma_f32_16x16x32_bf16(ah1, bh, acc[1][ni], 0, 0, 0);
          }
        }
      } else {
        // x = h0buf (cross-XCD) and h = h1buf: both coherent loads
        #pragma unroll 4
        for (int kb = 0; kb < K_; kb += 32) {
          frag a0  = ld_coh(x0 + kb);
          frag a1  = ld_coh(x1 + kb);
          frag ah0 = ra0 ? zf : ld_coh(hp0 + kb);
          frag ah1 = ra1 ? zf : ld_coh(hp1 + kb);
          #pragma unroll
          for (int ni = 0; ni < 4; ++ni) {
            frag bx = *reinterpret_cast<const frag*>(wb + (size_t)ni * 16 * WPAD + kb);
            frag bh = *reinterpret_cast<const frag*>(wb + (size_t)ni * 16 * WPAD + 512 + kb);
            acc[0][ni] = __builtin_amdgcn_mfma_f32_16x16x32_bf16(a0,  bx, acc[0][ni], 0, 0, 0);
            acc[1][ni] = __builtin_amdgcn_mfma_f32_16x16x32_bf16(a1,  bx, acc[1][ni], 0, 0, 0);
            acc[0][ni] = __builtin_amdgcn_mfma_f32_16x16x32_bf16(ah0, bh, acc[0][ni], 0, 0, 0);
            acc[1][ni] = __builtin_amdgcn_mfma_f32_16x16x32_bf16(ah1, bh, acc[1][ni], 0, 0, 0);
          }
        }
      }

      // cell elementwise: fully lane-local (ni = gate, same col r16)
      float* hidden_t = hidden + (size_t)t * B_ * H_;
      #pragma unroll
      for (int mi = 0; mi < 2; ++mi) {
        #pragma unroll
        for (int j = 0; j < 4; ++j) {
          const int lrow = wrow_local + mi * 16 + kq * 4 + j;
          const int row  = rowbase + lrow;
          const int col  = hbase + r16;
          float gi = acc[mi][0][j] + bias[0];
          float gf = acc[mi][1][j] + bias[1];
          float gg = acc[mi][2][j] + bias[2];
          float go = acc[mi][3][j] + bias[3];
          float iv = 1.f / (1.f + __expf(-gi));
          float fv = 1.f / (1.f + __expf(-gf));
          float gv = 1.f - 2.f / (__expf(2.f * gg) + 1.f);   // tanh
          float ov = 1.f / (1.f + __expf(-go));
          float ce = rstlds[lrow] ? 0.f : creg[mi][j];
          float cnew = fv * ce + iv * gv;
          float hnew = ov * (1.f - 2.f / (__expf(2.f * cnew) + 1.f));
          creg[mi][j] = cnew;
          const size_t off = (size_t)row * H_ + col;
          bf16 hb = __float2bfloat16(hnew);
          hstage[wave][mi * 16 + kq * 4 + j][r16] = *reinterpret_cast<u16*>(&hb);
          if (layer) hidden_t[off] = hnew;                 // plain cached store
          if (t == T_ - 1) {
            hn[(size_t)layer * B_ * H_ + off] = hnew;
            cn[(size_t)layer * B_ * H_ + off] = cnew;
          }
        }
      }

      // packed coherent h stores: wave-local LDS tile -> 8B agent-scope stores
      #pragma unroll
      for (int q = 0; q < 2; ++q) {
        int idx = q * 64 + lane;
        int row = idx >> 2;                  // 0..31
        int c4  = idx & 3;                   // 8B chunk within 16-col segment
        u64 v = *reinterpret_cast<const u64*>(&hstage[wave][row][c4 * 4]);
        u16* dst = Hn + (size_t)(wrow0 + row) * H_ + hbase + c4 * 4;
        __hip_atomic_store((u64*)dst, v, __ATOMIC_RELAXED, __HIP_MEMORY_SCOPE_AGENT);
      }
    }

    // pair-domain barrier: no fences, relaxed atomics only
    if (p < T_) {
      asm volatile("s_waitcnt vmcnt(0)" ::: "memory");  // h stores acked at coherent point
      __syncthreads();
      if (tid == 0) {
        __hip_atomic_fetch_add(pairctr, 1, __ATOMIC_RELAXED, __HIP_MEMORY_SCOPE_AGENT);
        const int target = 64 * (p + 1);
        while (__hip_atomic_load(pairctr, __ATOMIC_RELAXED, __HIP_MEMORY_SCOPE_AGENT) < target)
          __builtin_amdgcn_s_sleep(2);
      }
      __syncthreads();
    }
  }
}

// ---------------- host ----------------

extern "C" void kernel_launch(void* const* d_in, const int* in_sizes, int n_in,
                              void* d_out, int out_size, void* d_ws, size_t ws_size,
                              hipStream_t stream) {
  (void)in_sizes; (void)n_in; (void)out_size; (void)ws_size;

  const float* latent = (const float*)d_in[0];
  const float* h0in   = (const float*)d_in[1];
  const float* c0in   = (const float*)d_in[2];
  const int*   reset  = (const int*)d_in[3];
  const float* W_ih0  = (const float*)d_in[4];
  const float* W_hh0  = (const float*)d_in[5];
  const float* b_ih0  = (const float*)d_in[6];
  const float* b_hh0  = (const float*)d_in[7];
  const float* W_ih1  = (const float*)d_in[8];
  const float* W_hh1  = (const float*)d_in[9];
  const float* b_ih1  = (const float*)d_in[10];
  const float* b_hh1  = (const float*)d_in[11];

  float* out    = (float*)d_out;
  float* hidden = out;                               // (T,B,H)
  float* hn     = out + (size_t)T_ * B_ * H_;        // (2,B,H)
  float* cn     = hn + (size_t)2 * B_ * H_;          // (2,B,H)

  // workspace layout
  char* ws = (char*)d_ws;
  u16* latb  = (u16*)ws;                             // T*B*K bf16 (64 MiB)
  u16* wih0b = latb + (size_t)T_ * B_ * K_;
  u16* whh0b = wih0b + (size_t)G4_ * K_;
  u16* wih1b = whh0b + (size_t)G4_ * K_;
  u16* whh1b = wih1b + (size_t)G4_ * K_;
  float* bsum0 = (float*)(whh1b + (size_t)G4_ * K_);
  float* bsum1 = bsum0 + G4_;
  u16* h0buf = (u16*)(bsum1 + G4_);                  // [2][B][H]
  u16* h1buf = h0buf + (size_t)2 * B_ * H_;
  int* ctr   = (int*)(h1buf + (size_t)2 * B_ * H_);  // 128 ints (4 x stride 32)

  // conversions / init (stream-ordered)
  int n_lat4 = T_ * B_ * K_ / 4;
  k_f32_to_bf16_v4<<<2048, 256, 0, stream>>>((const float4*)latent, (ushort4*)latb, n_lat4);
  int n_w4 = G4_ * K_ / 4;
  k_f32_to_bf16_v4<<<256, 256, 0, stream>>>((const float4*)W_ih0, (ushort4*)wih0b, n_w4);
  k_f32_to_bf16_v4<<<256, 256, 0, stream>>>((const float4*)W_hh0, (ushort4*)whh0b, n_w4);
  k_f32_to_bf16_v4<<<256, 256, 0, stream>>>((const float4*)W_ih1, (ushort4*)wih1b, n_w4);
  k_f32_to_bf16_v4<<<256, 256, 0, stream>>>((const float4*)W_hh1, (ushort4*)whh1b, n_w4);
  k_bias<<<(G4_ + 255) / 256, 256, 0, stream>>>(b_ih0, b_hh0, b_ih1, b_hh1, bsum0, bsum1);
  k_init2<<<(B_ * H_ + 255) / 256, 256, 0, stream>>>(h0in, h0buf, h1buf);
  k_zero<<<1, 128, 0, stream>>>(ctr);

  // persistent cooperative kernel
  hipFuncSetAttribute((const void*)k_main, hipFuncAttributeMaxDynamicSharedMemorySize,
                      (int)SMEM_BYTES);
  void* args[] = { (void*)&latb, (void*)&wih0b, (void*)&whh0b, (void*)&wih1b, (void*)&whh1b,
                   (void*)&bsum0, (void*)&bsum1, (void*)&reset, (void*)&c0in,
                   (void*)&h0buf, (void*)&h1buf, (void*)&hidden, (void*)&hn, (void*)&cn,
                   (void*)&ctr };
  hipLaunchCooperativeKernel((void*)k_main, dim3(NWG), dim3(256), args,
                             (unsigned int)SMEM_BYTES, stream);
}

// Round 6
// 1825.578 us; speedup vs baseline: 5.3825x; 1.0949x over previous
//
#include <hip/hip_runtime.h>
#include <hip/hip_bf16.h>

typedef __hip_bfloat16 bf16;
typedef unsigned short u16;
typedef unsigned long long u64;
using frag  = __attribute__((ext_vector_type(8))) short;   // 8 bf16
using f32x4 = __attribute__((ext_vector_type(4))) float;   // 4 fp32 acc

static constexpr int T_  = 128;
static constexpr int B_  = 512;
static constexpr int H_  = 512;
static constexpr int K_  = 512;
static constexpr int G4_ = 2048;
static constexpr int NWG = 256;
static constexpr int WPAD = 1032;                     // bf16 per LDS row: 1024 + 8 pad
static constexpr size_t SMEM_BYTES = 64 * WPAD * 2;   // 132096 B dynamic

// coherent (agent-scope, L1/L2-bypassing) 16B load as 2x b64 relaxed atomics
__device__ __forceinline__ frag ld_coh(const u16* p) {
  u64 lo = __hip_atomic_load((const u64*)p,       __ATOMIC_RELAXED, __HIP_MEMORY_SCOPE_AGENT);
  u64 hi = __hip_atomic_load((const u64*)(p + 4), __ATOMIC_RELAXED, __HIP_MEMORY_SCOPE_AGENT);
  union { u64 q[2]; frag f; } u;
  u.q[0] = lo; u.q[1] = hi;
  return u.f;
}

// ---------------- setup kernels ----------------

__global__ void k_f32_to_bf16_v4(const float4* __restrict__ src,
                                 ushort4* __restrict__ dst, int n4) {
  int i = blockIdx.x * blockDim.x + threadIdx.x;
  int stride = gridDim.x * blockDim.x;
  for (; i < n4; i += stride) {
    float4 v = src[i];
    ushort4 o;
    bf16 t0 = __float2bfloat16(v.x); o.x = *reinterpret_cast<u16*>(&t0);
    bf16 t1 = __float2bfloat16(v.y); o.y = *reinterpret_cast<u16*>(&t1);
    bf16 t2 = __float2bfloat16(v.z); o.z = *reinterpret_cast<u16*>(&t2);
    bf16 t3 = __float2bfloat16(v.w); o.w = *reinterpret_cast<u16*>(&t3);
    dst[i] = o;
  }
}

__global__ void k_bias(const float* __restrict__ bih0, const float* __restrict__ bhh0,
                       const float* __restrict__ bih1, const float* __restrict__ bhh1,
                       float* __restrict__ bsum0, float* __restrict__ bsum1) {
  int i = blockIdx.x * blockDim.x + threadIdx.x;
  if (i < G4_) {
    bsum0[i] = bih0[i] + bhh0[i];
    bsum1[i] = bih1[i] + bhh1[i];
  }
}

// initial h: layer0 -> h0buf parity 0, layer1 -> h1buf parity 1
__global__ void k_init2(const float* __restrict__ h0,
                        u16* __restrict__ h0buf, u16* __restrict__ h1buf) {
  int i = blockIdx.x * blockDim.x + threadIdx.x;
  int n = B_ * H_;
  if (i < n) {
    bf16 a = __float2bfloat16(h0[i]);
    bf16 b = __float2bfloat16(h0[n + i]);
    h0buf[i] = *reinterpret_cast<u16*>(&a);          // parity 0
    h1buf[n + i] = *reinterpret_cast<u16*>(&b);      // parity 1
  }
}

__global__ void k_zero(int* p) {
  int i = blockIdx.x * blockDim.x + threadIdx.x;
  if (i < 128) p[i] = 0;
}

// ---------------- persistent LSTM kernel ----------------
// 256 WGs x 512 thr (8 waves -> 2 waves/SIMD). XCD-locality mapping:
//   lb = wg & 7 : layer = lb>>2, bg = lb&3 ; cg = wg >> 3 (0..31)
// WG owns batch rows [bg*128,+128) x h-cols [cg*16,+16); wave w owns rows
// [bg*128 + w*16, +16). Weights (64 gate-rows, W_ih||W_hh) in LDS, staged once.
// Phase p: layer0 computes t=p, layer1 computes t=p-1.
// Sync: per (bg) pair-domain, per-layer counters (32 arrivals each); WG adds to
// its layer's counter (relaxed agent RMW), polls BOTH >= 32*(p+1). No cache-
// maintenance fences: all cross-WG h data moves via agent-scope relaxed atomics.
// c-state in registers; hidden/hn/cn stores deferred past barrier arrival.
__global__ __launch_bounds__(512, 2)
void k_main(const u16* __restrict__ latb,
            const u16* __restrict__ W0i, const u16* __restrict__ W0h,
            const u16* __restrict__ W1i, const u16* __restrict__ W1h,
            const float* __restrict__ bs0, const float* __restrict__ bs1,
            const int* __restrict__ reset,   // (T,B)
            const float* __restrict__ c0,    // (2,B,H)
            u16* __restrict__ h0buf,         // [2][B][H]
            u16* __restrict__ h1buf,         // [2][B][H]
            float* __restrict__ hidden,      // (T,B,H)
            float* __restrict__ hn,          // (2,B,H)
            float* __restrict__ cn,          // (2,B,H)
            int* __restrict__ ctr) {         // 128 ints: [bg*32]=L0, [bg*32+16]=L1
  extern __shared__ char smem_raw[];
  u16* wlds = (u16*)smem_raw;                // [64][WPAD]
  __shared__ int rstlds[128];
  __shared__ float hstage[8][16][20];        // per-wave h tile (padded, 16B-aligned rows)

  const int tid   = threadIdx.x;
  const int wg    = blockIdx.x;
  const int lb    = wg & 7;
  const int layer = lb >> 2;
  const int bg    = lb & 3;
  const int cg    = wg >> 3;
  const int hbase = cg * 16;
  const int rowbase = bg * 128;
  const int wave  = tid >> 6;                  // 0..7
  const int lane  = tid & 63;
  const int r16   = lane & 15;
  const int kq    = lane >> 4;                 // 0..3
  const int wrow_local = wave * 16;            // wave's batch offset within WG
  const int wrow0 = rowbase + wrow_local;

  const u16* Wih = layer ? W1i : W0i;
  const u16* Whh = layer ? W1h : W0h;
  const float* bs = layer ? bs1 : bs0;
  u16* hself = layer ? h1buf : h0buf;
  int* ctrSelf  = ctr + bg * 32 + (layer ? 16 : 0);
  int* ctrOther = ctr + bg * 32 + (layer ? 0 : 16);

  // ---- stage weights into LDS (once): row r -> gate r>>4, h-col hbase + (r&15)
  for (int c = 0; c < 16; ++c) {
    int chunk = c * 512 + tid;                 // 8192 chunks of 16B
    int row = chunk >> 7;                      // 128 chunks per row
    int inb = (chunk & 127) * 16;              // byte offset in row (0..2047)
    int grow = (row >> 4) * H_ + hbase + (row & 15);
    const char* src = (inb < 1024)
        ? (const char*)(Wih + (size_t)grow * K_) + inb
        : (const char*)(Whh + (size_t)grow * K_) + (inb - 1024);
    char* dst = (char*)(wlds + (size_t)row * WPAD) + inb;
    *(float4*)dst = *(const float4*)src;
  }

  // per-lane gate biases (col = hbase + r16)
  float bias[4];
  #pragma unroll
  for (int g = 0; g < 4; ++g) bias[g] = bs[g * H_ + hbase + r16];

  // c-state registers: j -> row = wrow0 + kq*4 + j, col = hbase + r16
  float creg[4];
  #pragma unroll
  for (int j = 0; j < 4; ++j)
    creg[j] = c0[((size_t)layer * B_ + (wrow0 + kq * 4 + j)) * H_ + hbase + r16];

  __syncthreads();

  const u16* wb = wlds + (size_t)r16 * WPAD + kq * 8;

  for (int p = 0; p <= T_; ++p) {
    const int t = layer ? (p - 1) : p;
    const bool active = (t >= 0 && t < T_);
    float hnew_r[4], cnew_r[4];

    if (active) {
      if (tid < 128) rstlds[tid] = reset[(size_t)t * B_ + rowbase + tid];
      __syncthreads();

      const u16* X  = layer ? (h0buf + (size_t)(p & 1) * B_ * H_)
                            : (latb + (size_t)t * B_ * K_);
      const u16* Hp = hself + (size_t)(p & 1) * B_ * H_;
      u16* Hn       = hself + (size_t)((p + 1) & 1) * B_ * H_;

      const int ra0 = rstlds[wrow_local + r16];
      const u16* x0  = X  + (size_t)(wrow0 + r16) * K_ + kq * 8;
      const u16* hp0 = Hp + (size_t)(wrow0 + r16) * H_ + kq * 8;

      f32x4 acc[4] = {};
      const frag zf = {};

      if (layer == 0) {
        #pragma unroll
        for (int kb = 0; kb < K_; kb += 32) {
          frag a  = *reinterpret_cast<const frag*>(x0 + kb);
          frag ah = ra0 ? zf : ld_coh(hp0 + kb);
          #pragma unroll
          for (int ni = 0; ni < 4; ++ni) {
            frag bx = *reinterpret_cast<const frag*>(wb + (size_t)ni * 16 * WPAD + kb);
            frag bh = *reinterpret_cast<const frag*>(wb + (size_t)ni * 16 * WPAD + 512 + kb);
            acc[ni] = __builtin_amdgcn_mfma_f32_16x16x32_bf16(a,  bx, acc[ni], 0, 0, 0);
            acc[ni] = __builtin_amdgcn_mfma_f32_16x16x32_bf16(ah, bh, acc[ni], 0, 0, 0);
          }
        }
      } else {
        #pragma unroll
        for (int kb = 0; kb < K_; kb += 32) {
          frag a  = ld_coh(x0 + kb);
          frag ah = ra0 ? zf : ld_coh(hp0 + kb);
          #pragma unroll
          for (int ni = 0; ni < 4; ++ni) {
            frag bx = *reinterpret_cast<const frag*>(wb + (size_t)ni * 16 * WPAD + kb);
            frag bh = *reinterpret_cast<const frag*>(wb + (size_t)ni * 16 * WPAD + 512 + kb);
            acc[ni] = __builtin_amdgcn_mfma_f32_16x16x32_bf16(a,  bx, acc[ni], 0, 0, 0);
            acc[ni] = __builtin_amdgcn_mfma_f32_16x16x32_bf16(ah, bh, acc[ni], 0, 0, 0);
          }
        }
      }

      // cell elementwise: lane-local (4 outputs: rows kq*4+j, col r16)
      #pragma unroll
      for (int j = 0; j < 4; ++j) {
        const int lrow = wrow_local + kq * 4 + j;
        float gi = acc[0][j] + bias[0];
        float gf = acc[1][j] + bias[1];
        float gg = acc[2][j] + bias[2];
        float go = acc[3][j] + bias[3];
        float iv = 1.f / (1.f + __expf(-gi));
        float fv = 1.f / (1.f + __expf(-gf));
        float gv = 1.f - 2.f / (__expf(2.f * gg) + 1.f);   // tanh
        float ov = 1.f / (1.f + __expf(-go));
        float ce = rstlds[lrow] ? 0.f : creg[j];
        float cnew = fv * ce + iv * gv;
        float hnew = ov * (1.f - 2.f / (__expf(2.f * cnew) + 1.f));
        creg[j] = cnew;
        cnew_r[j] = cnew;
        hnew_r[j] = hnew;
        hstage[wave][kq * 4 + j][r16] = hnew;   // wave-local LDS
      }

      // pack + coherent h stores: lane -> (row = lane>>2, 4 cols at (lane&3)*4)
      {
        const int prow = lane >> 2;
        const int pc4  = lane & 3;
        float4 v = *reinterpret_cast<const float4*>(&hstage[wave][prow][pc4 * 4]);
        bf16 b0 = __float2bfloat16(v.x), b1 = __float2bfloat16(v.y);
        bf16 b2 = __float2bfloat16(v.z), b3 = __float2bfloat16(v.w);
        u64 pk = (u64)*reinterpret_cast<u16*>(&b0)
               | ((u64)*reinterpret_cast<u16*>(&b1) << 16)
               | ((u64)*reinterpret_cast<u16*>(&b2) << 32)
               | ((u64)*reinterpret_cast<u16*>(&b3) << 48);
        u16* dst = Hn + (size_t)(wrow0 + prow) * H_ + hbase + pc4 * 4;
        __hip_atomic_store((u64*)dst, pk, __ATOMIC_RELAXED, __HIP_MEMORY_SCOPE_AGENT);
      }
    }

    // barrier arrival (h stores drained by the barrier's implicit vmcnt wait)
    if (p < T_) {
      asm volatile("s_waitcnt vmcnt(0)" ::: "memory");
      __syncthreads();
      if (tid == 0)
        __hip_atomic_fetch_add(ctrSelf, 1, __ATOMIC_RELAXED, __HIP_MEMORY_SCOPE_AGENT);
    }

    // deferred output stores (overlap with poll; nobody reads these in-kernel)
    if (active) {
      float* hidden_t = hidden + (size_t)t * B_ * H_;
      #pragma unroll
      for (int j = 0; j < 4; ++j) {
        const size_t off = (size_t)(wrow0 + kq * 4 + j) * H_ + hbase + r16;
        if (layer) hidden_t[off] = hnew_r[j];
        if (t == T_ - 1) {
          hn[(size_t)layer * B_ * H_ + off] = hnew_r[j];
          cn[(size_t)layer * B_ * H_ + off] = cnew_r[j];
        }
      }
    }

    // barrier wait: both layer counters of this pair-domain at phase p+1
    if (p < T_) {
      if (tid == 0) {
        const int target = 32 * (p + 1);
        while (true) {
          int a = __hip_atomic_load(ctrSelf,  __ATOMIC_RELAXED, __HIP_MEMORY_SCOPE_AGENT);
          int b = __hip_atomic_load(ctrOther, __ATOMIC_RELAXED, __HIP_MEMORY_SCOPE_AGENT);
          if (a >= target && b >= target) break;
          __builtin_amdgcn_s_sleep(2);
        }
      }
      __syncthreads();
    }
  }
}

// ---------------- host ----------------

extern "C" void kernel_launch(void* const* d_in, const int* in_sizes, int n_in,
                              void* d_out, int out_size, void* d_ws, size_t ws_size,
                              hipStream_t stream) {
  (void)in_sizes; (void)n_in; (void)out_size; (void)ws_size;

  const float* latent = (const float*)d_in[0];
  const float* h0in   = (const float*)d_in[1];
  const float* c0in   = (const float*)d_in[2];
  const int*   reset  = (const int*)d_in[3];
  const float* W_ih0  = (const float*)d_in[4];
  const float* W_hh0  = (const float*)d_in[5];
  const float* b_ih0  = (const float*)d_in[6];
  const float* b_hh0  = (const float*)d_in[7];
  const float* W_ih1  = (const float*)d_in[8];
  const float* W_hh1  = (const float*)d_in[9];
  const float* b_ih1  = (const float*)d_in[10];
  const float* b_hh1  = (const float*)d_in[11];

  float* out    = (float*)d_out;
  float* hidden = out;                               // (T,B,H)
  float* hn     = out + (size_t)T_ * B_ * H_;        // (2,B,H)
  float* cn     = hn + (size_t)2 * B_ * H_;          // (2,B,H)

  // workspace layout
  char* ws = (char*)d_ws;
  u16* latb  = (u16*)ws;                             // T*B*K bf16 (64 MiB)
  u16* wih0b = latb + (size_t)T_ * B_ * K_;
  u16* whh0b = wih0b + (size_t)G4_ * K_;
  u16* wih1b = whh0b + (size_t)G4_ * K_;
  u16* whh1b = wih1b + (size_t)G4_ * K_;
  float* bsum0 = (float*)(whh1b + (size_t)G4_ * K_);
  float* bsum1 = bsum0 + G4_;
  u16* h0buf = (u16*)(bsum1 + G4_);                  // [2][B][H]
  u16* h1buf = h0buf + (size_t)2 * B_ * H_;
  int* ctr   = (int*)(h1buf + (size_t)2 * B_ * H_);  // 128 ints

  // conversions / init (stream-ordered)
  int n_lat4 = T_ * B_ * K_ / 4;
  k_f32_to_bf16_v4<<<2048, 256, 0, stream>>>((const float4*)latent, (ushort4*)latb, n_lat4);
  int n_w4 = G4_ * K_ / 4;
  k_f32_to_bf16_v4<<<256, 256, 0, stream>>>((const float4*)W_ih0, (ushort4*)wih0b, n_w4);
  k_f32_to_bf16_v4<<<256, 256, 0, stream>>>((const float4*)W_hh0, (ushort4*)whh0b, n_w4);
  k_f32_to_bf16_v4<<<256, 256, 0, stream>>>((const float4*)W_ih1, (ushort4*)wih1b, n_w4);
  k_f32_to_bf16_v4<<<256, 256, 0, stream>>>((const float4*)W_hh1, (ushort4*)whh1b, n_w4);
  k_bias<<<(G4_ + 255) / 256, 256, 0, stream>>>(b_ih0, b_hh0, b_ih1, b_hh1, bsum0, bsum1);
  k_init2<<<(B_ * H_ + 255) / 256, 256, 0, stream>>>(h0in, h0buf, h1buf);
  k_zero<<<1, 128, 0, stream>>>(ctr);

  // persistent cooperative kernel
  hipFuncSetAttribute((const void*)k_main, hipFuncAttributeMaxDynamicSharedMemorySize,
                      (int)SMEM_BYTES);
  void* args[] = { (void*)&latb, (void*)&wih0b, (void*)&whh0b, (void*)&wih1b, (void*)&whh1b,
                   (void*)&bsum0, (void*)&bsum1, (void*)&reset, (void*)&c0in,
                   (void*)&h0buf, (void*)&h1buf, (void*)&hidden, (void*)&hn, (void*)&cn,
                   (void*)&ctr };
  hipLaunchCooperativeKernel((void*)k_main, dim3(NWG), dim3(512), args,
                             (unsigned int)SMEM_BYTES, stream);
}